// Round 8
// baseline (3673.569 us; speedup 1.0000x reference)
//
#include <hip/hip_runtime.h>
#include <hip/hip_bf16.h>
#include <hip/hip_fp16.h>

#define T_ 512
#define B_ 128
#define E_ 256
#define H_ 256

typedef _Float16 h8 __attribute__((ext_vector_type(8)));
typedef float    f4 __attribute__((ext_vector_type(4)));
typedef unsigned u4 __attribute__((ext_vector_type(4)));

// ---------------------------------------------------------------------------
// K1: embedding gather + fp32->fp16, MFMA A-fragment order:
// h8 index = (t*64 + grp*8 + kb)*64 + lane, holding
// x[t][b = grp*16 + (lane&15)][e = kb*32 + (lane>>4)*8 + j], j=0..7
// ---------------------------------------------------------------------------
__global__ __launch_bounds__(256) void k_gather(const int* __restrict__ tok,
        const float* __restrict__ emb, _Float16* __restrict__ x16)
{
    const int t = blockIdx.x;
    const int tid = threadIdx.x;
    const int wave = tid >> 6, lane = tid & 63;
    const int q = lane >> 4, l16 = lane & 15;
    __shared__ int rows[B_];
    if (tid < B_) rows[tid] = tok[(size_t)tid * T_ + t];
    __syncthreads();
    for (int it = 0; it < 16; ++it) {
        int pair = it * 4 + wave;          // pair = grp*8 + kb
        int grp = pair >> 3, kb = pair & 7;
        int b = grp * 16 + l16;
        int e = kb * 32 + q * 8;
        const float* src = emb + (size_t)rows[b] * E_ + e;
        float4 a = *(const float4*)src;
        float4 c = *(const float4*)(src + 4);
        h8 hv;
        hv[0]=(_Float16)a.x; hv[1]=(_Float16)a.y; hv[2]=(_Float16)a.z; hv[3]=(_Float16)a.w;
        hv[4]=(_Float16)c.x; hv[5]=(_Float16)c.y; hv[6]=(_Float16)c.z; hv[7]=(_Float16)c.w;
        *(h8*)(x16 + (((size_t)t * 64 + pair) * 64 + lane) * 8) = hv;
    }
}

// ---------------------------------------------------------------------------
// K2: weight permute+convert to fp16 B-fragment layout.
// wp element [(d*32 + mat*16 + p*4 + w)*16384 + nt*4096 + n*256 + k] =
//   M[k][nt*256 + p*64 + w*16 + n],  M = (mat? U : W) of direction d.
// One block per (d, mat, p, w) = 64 blocks.
// ---------------------------------------------------------------------------
__global__ __launch_bounds__(256) void k_perm(const float* __restrict__ Wf, const float* __restrict__ Uf,
        const float* __restrict__ Wb, const float* __restrict__ Ub, _Float16* __restrict__ wp)
{
    const int bid = blockIdx.x;
    const int d = bid >> 5, mat = (bid >> 4) & 1, p = (bid >> 2) & 3, w = bid & 3;
    const float* src = d ? (mat ? Ub : Wb) : (mat ? Uf : Wf);
    _Float16* dst = wp + (size_t)bid * 16384;
    const int tid = threadIdx.x;
    const int cbase = p * 64 + w * 16;
    __shared__ float S[256][17];
    for (int nt = 0; nt < 4; ++nt) {
        for (int it = 0; it < 16; ++it) {
            int idx = it * 256 + tid;
            int k = idx >> 4, c16 = idx & 15;
            S[k][c16] = src[(size_t)k * 1024 + nt * 256 + cbase + c16];
        }
        __syncthreads();
        for (int it = 0; it < 16; ++it) {
            int idx = it * 256 + tid;
            int k = idx & 255, c16 = idx >> 8;
            dst[(size_t)nt * 4096 + c16 * 256 + k] = (_Float16)S[k][c16];
        }
        __syncthreads();
    }
}

// ---------------------------------------------------------------------------
// K3: fused recurrence. 64 WGs = (d, p quarter of units, grp of 16 rows);
// wave w owns 16 units with the full K=512 weight slice register-resident.
// h exchange: tagged dwords, stores ALWAYS write-through (sc0 sc1 -> LLC +
// local L2). Poll alternates XCD-local rounds (sc0, ~200cyc) with LLC
// rounds (sc0 sc1, ~900cyc): converges on the cheap round when peers share
// an XCD, guaranteed progress via the LLC round otherwise. No handshake,
// no fences, no __syncthreads in the loop; placement affects speed only.
// ---------------------------------------------------------------------------
__device__ __forceinline__ float fsig(float x) {
    float t = __expf(-fabsf(x));
    float r = __builtin_amdgcn_rcpf(1.0f + t);
    return x >= 0.f ? r : 1.0f - r;
}
__device__ __forceinline__ float ftanh(float x) {
    float t = __expf(-2.0f * fabsf(x));
    float r = (1.0f - t) * __builtin_amdgcn_rcpf(1.0f + t);
    return x >= 0.f ? r : -r;
}

#define PLD(i, P, OFF, SC) \
    asm volatile("global_load_dwordx4 %0, %1, off offset:" OFF " " SC \
                 : "=v"(pd[i]) : "v"(P) : "memory")
#define POLL16(SC) \
    PLD(0,pb0,"0",SC);  PLD(1,pb0,"16",SC);  PLD(2,pb0,"128",SC);  PLD(3,pb0,"144",SC); \
    PLD(4,pb1,"0",SC);  PLD(5,pb1,"16",SC);  PLD(6,pb1,"128",SC);  PLD(7,pb1,"144",SC); \
    PLD(8,pb2,"0",SC);  PLD(9,pb2,"16",SC);  PLD(10,pb2,"128",SC); PLD(11,pb2,"144",SC); \
    PLD(12,pb3,"0",SC); PLD(13,pb3,"16",SC); PLD(14,pb3,"128",SC); PLD(15,pb3,"144",SC)

__global__ __launch_bounds__(256, 1) __attribute__((amdgpu_waves_per_eu(1, 1)))
void k_rnn(const _Float16* __restrict__ x16, const _Float16* __restrict__ wp,
           const float* __restrict__ bf, const float* __restrict__ bb,
           unsigned* __restrict__ hx, float* __restrict__ hfin)
{
    const int wg = blockIdx.x;           // 0..63 = d*32 + p*8 + grp
    const int d = wg >> 5;
    const int p = (wg >> 3) & 3;
    const int grp = wg & 7;
    const int tid = threadIdx.x;
    const int w = tid >> 6, lane = tid & 63;
    const int q = lane >> 4, l16 = lane & 15;

    // weights: wx (E half) + wu (H half): 64 h8 = 256 regs, operand-resident
    h8 wx[4][8], wu[4][8];
    {
        const _Float16* bx = wp + (size_t)(d * 32 + 0  + p * 4 + w) * 16384;
        const _Float16* bu = wp + (size_t)(d * 32 + 16 + p * 4 + w) * 16384;
        #pragma unroll
        for (int nt = 0; nt < 4; ++nt)
            #pragma unroll
            for (int kb = 0; kb < 8; ++kb) {
                wx[nt][kb] = *(const h8*)(bx + nt * 4096 + l16 * 256 + kb * 32 + q * 8);
                wu[nt][kb] = *(const h8*)(bu + nt * 4096 + l16 * 256 + kb * 32 + q * 8);
            }
        #pragma unroll
        for (int nt = 0; nt < 4; ++nt)
            #pragma unroll
            for (int kb = 0; kb < 8; ++kb) {
                asm volatile("" : "+v"(wx[nt][kb]));
                asm volatile("" : "+v"(wu[nt][kb]));
            }
    }
    const float* bias = d ? bb : bf;
    float bv[4];
    #pragma unroll
    for (int g = 0; g < 4; ++g)
        bv[g] = bias[g * 256 + p * 64 + w * 16 + l16];

    unsigned* gbase = hx + (size_t)(d * 8 + grp) * 8192;  // [par 2][blk 4][row 16][unit 64]

    // x fragments, double-buffered 2 steps deep
    h8 xf[2][8];
    {
        int xt0 = d ? (T_ - 1) : 0;
        int xt1 = d ? (T_ - 2) : 1;
        const h8* x0 = (const h8*)x16 + ((size_t)xt0 * 64 + grp * 8) * 64 + lane;
        const h8* x1 = (const h8*)x16 + ((size_t)xt1 * 64 + grp * 8) * 64 + lane;
        #pragma unroll
        for (int kb = 0; kb < 8; ++kb) { xf[0][kb] = x0[kb * 64]; xf[1][kb] = x1[kb * 64]; }
    }

    float c4[4] = {0.f, 0.f, 0.f, 0.f};
    float hv4[4] = {0.f, 0.f, 0.f, 0.f};

    for (int s = 0; s < T_; ++s) {
        f4 acc[4];
        #pragma unroll
        for (int nt = 0; nt < 4; ++nt)
            acc[nt] = (f4){bv[nt], bv[nt], bv[nt], bv[nt]};
        // x @ W (overlaps peers' h-publish visibility)
        #pragma unroll
        for (int kb = 0; kb < 8; ++kb)
            #pragma unroll
            for (int nt = 0; nt < 4; ++nt)
                acc[nt] = __builtin_amdgcn_mfma_f32_16x16x32_f16(xf[s & 1][kb], wx[nt][kb], acc[nt], 0, 0, 0);

        if (s > 0) {
            const int pp = (s - 1) & 1;
            const unsigned etag = (unsigned)s << 16;
            const unsigned* pb0 = gbase + (size_t)pp * 4096 + l16 * 64 + q * 8;
            const unsigned* pb1 = pb0 + 1024;
            const unsigned* pb2 = pb0 + 2048;
            const unsigned* pb3 = pb0 + 3072;
            u4 pd[16];
            int round = 0;
            while (true) {
                if ((round & 1) == 0) { POLL16("sc0"); }        // XCD-local L2 round
                else                  { POLL16("sc0 sc1"); }    // LLC round (guaranteed progress)
                asm volatile("s_waitcnt vmcnt(0)"
                    : "+v"(pd[0]), "+v"(pd[1]), "+v"(pd[2]), "+v"(pd[3]),
                      "+v"(pd[4]), "+v"(pd[5]), "+v"(pd[6]), "+v"(pd[7]),
                      "+v"(pd[8]), "+v"(pd[9]), "+v"(pd[10]), "+v"(pd[11]),
                      "+v"(pd[12]), "+v"(pd[13]), "+v"(pd[14]), "+v"(pd[15])
                    :: "memory");
                unsigned bad = 0;
                #pragma unroll
                for (int j = 0; j < 16; ++j)
                    #pragma unroll
                    for (int e = 0; e < 4; ++e)
                        bad |= (pd[j][e] ^ etag) & 0xffff0000u;
                if (__ballot(bad != 0) == 0ull) break;
                ++round;
            }
            // extract h fragments (low16) and do h @ U
            h8 hf[8];
            #pragma unroll
            for (int kb2 = 0; kb2 < 4; ++kb2)
                #pragma unroll
                for (int half = 0; half < 2; ++half) {
                    u4 a = pd[kb2 * 4 + half * 2];
                    u4 b = pd[kb2 * 4 + half * 2 + 1];
                    u4 hh;
                    hh[0] = (a[0] & 0xffffu) | (a[1] << 16);
                    hh[1] = (a[2] & 0xffffu) | (a[3] << 16);
                    hh[2] = (b[0] & 0xffffu) | (b[1] << 16);
                    hh[3] = (b[2] & 0xffffu) | (b[3] << 16);
                    hf[kb2 * 2 + half] = __builtin_bit_cast(h8, hh);
                }
            #pragma unroll
            for (int kb = 0; kb < 8; ++kb)
                #pragma unroll
                for (int nt = 0; nt < 4; ++nt)
                    acc[nt] = __builtin_amdgcn_mfma_f32_16x16x32_f16(hf[kb], wu[nt][kb], acc[nt], 0, 0, 0);
        }
        // gates
        #pragma unroll
        for (int r = 0; r < 4; ++r) {
            float zi = acc[0][r];
            float zf = acc[1][r];
            float zg = acc[2][r];
            float zo = acc[3][r];
            float cn = fsig(zf) * c4[r] + fsig(zi) * ftanh(zg);
            c4[r] = cn;
            hv4[r] = fsig(zo) * ftanh(cn);
        }
        if (s < T_ - 1) {
            // publish h_s as tagged dwords, write-through (LLC + local L2)
            const unsigned otag = (unsigned)(s + 1) << 16;
            unsigned* ob = gbase + (size_t)(s & 1) * 4096 + p * 1024 + w * 16 + l16;
            #pragma unroll
            for (int r = 0; r < 4; ++r) {
                _Float16 hh = (_Float16)hv4[r];
                unsigned v = otag | (unsigned)__builtin_bit_cast(unsigned short, hh);
                unsigned* ptr = ob + (q * 4 + r) * 64;
                asm volatile("global_store_dword %0, %1, off sc0 sc1" :: "v"(ptr), "v"(v) : "memory");
            }
            // prefetch x fragments for step s+2 (full step of latency cover)
            if (s + 2 < T_) {
                int xt = d ? (T_ - 3 - s) : (s + 2);
                const h8* xb = (const h8*)x16 + ((size_t)xt * 64 + grp * 8) * 64 + lane;
                #pragma unroll
                for (int kb = 0; kb < 8; ++kb) xf[s & 1][kb] = xb[kb * 64];
            }
        }
    }
    // final h (fp32)
    #pragma unroll
    for (int r = 0; r < 4; ++r)
        hfin[((size_t)d * B_ + grp * 16 + q * 4 + r) * H_ + p * 64 + w * 16 + l16] = hv4[r];
}

// ---------------------------------------------------------------------------
// K4: head. One block per batch row: a1 = relu([h_fwd|h_bwd] @ W1 + b1),
// logits = a1 @ W2 + b2, softmax over 32 classes. All fp32.
// ---------------------------------------------------------------------------
__global__ __launch_bounds__(256) void k_head(const float* __restrict__ hfin,
        const float* __restrict__ W1, const float* __restrict__ b1,
        const float* __restrict__ W2, const float* __restrict__ b2, float* __restrict__ out)
{
    const int b = blockIdx.x;
    const int tid = threadIdx.x;
    __shared__ float hcat[2 * H_];
    __shared__ float a1[256];
    if (tid < 128) {
        if (tid < 64)
            ((float4*)hcat)[tid] = ((const float4*)(hfin + (size_t)b * H_))[tid];
        else
            ((float4*)(hcat + H_))[tid - 64] = ((const float4*)(hfin + (size_t)(B_ + b) * H_))[tid - 64];
    }
    __syncthreads();
    {
        float s = b1[tid];
        #pragma unroll 4
        for (int k = 0; k < 2 * H_; ++k)
            s += hcat[k] * W1[(size_t)k * 256 + tid];
        a1[tid] = s > 0.f ? s : 0.f;
    }
    __syncthreads();
    if (tid < 32) {
        float s = b2[tid];
        #pragma unroll 4
        for (int j = 0; j < 256; ++j)
            s += a1[j] * W2[(size_t)j * 32 + tid];
        float mx = s;
        #pragma unroll
        for (int o = 16; o > 0; o >>= 1)
            mx = fmaxf(mx, __shfl_xor(mx, o, 32));
        float e = __expf(s - mx);
        float sum = e;
        #pragma unroll
        for (int o = 16; o > 0; o >>= 1)
            sum += __shfl_xor(sum, o, 32);
        out[(size_t)b * 32 + tid] = e / sum;
    }
}

// ---------------------------------------------------------------------------
extern "C" void kernel_launch(void* const* d_in, const int* in_sizes, int n_in,
                              void* d_out, int out_size, void* d_ws, size_t ws_size,
                              hipStream_t stream)
{
    (void)in_sizes; (void)n_in; (void)out_size; (void)ws_size;
    const int*   tok = (const int*)d_in[0];
    const float* emb = (const float*)d_in[1];
    const float* Wf  = (const float*)d_in[2];
    const float* Uf  = (const float*)d_in[3];
    const float* bf  = (const float*)d_in[4];
    const float* Wb  = (const float*)d_in[5];
    const float* Ub  = (const float*)d_in[6];
    const float* bb  = (const float*)d_in[7];
    const float* W1  = (const float*)d_in[8];
    const float* b1  = (const float*)d_in[9];
    const float* W2  = (const float*)d_in[10];
    const float* b2  = (const float*)d_in[11];
    float* out = (float*)d_out;

    char* ws = (char*)d_ws;
    _Float16* x16   = (_Float16*)(ws);                 // 33,554,432 B frag-ordered x
    _Float16* wp    = (_Float16*)(ws + 33554432);      //  2,097,152 B permuted W+U fp16
    unsigned* hx    = (unsigned*)(ws + 35651584);      //    524,288 B tagged h exchange
    float*    hfin  = (float*)   (ws + 36175872);      //    262,144 B final h fp32
                                                       // total 36,438,016 B

    k_gather<<<T_, 256, 0, stream>>>(tok, emb, x16);
    k_perm  <<<64, 256, 0, stream>>>(Wf, Uf, Wb, Ub, wp);
    k_rnn   <<<64, 256, 0, stream>>>(x16, wp, bf, bb, hx, hfin);
    k_head  <<<B_, 256, 0, stream>>>(hfin, W1, b1, W2, b2, out);
}